// Round 12
// baseline (575.827 us; speedup 1.0000x reference)
//
#include <hip/hip_runtime.h>
#include <cmath>

#define NB 2
#define NN 2048
#define ND 128
#define NH 8
#define NL 3
#define NV 32
#define NDH 16
#define LN_EPS 1e-5f
/* ATT_SCALE(0.25) * log2(e), folded into Q at qkv-pack time so the attention
   inner loop is a raw exp2 per score. */
#define QSCALE 0.36067376022224085f
#define NBLK 512
#define SMEM_BYTES 68608

typedef __bf16 bf8_t __attribute__((ext_vector_type(8)));
typedef __bf16 bf4_t __attribute__((ext_vector_type(4)));
typedef float f4x __attribute__((ext_vector_type(4)));
typedef float f16x __attribute__((ext_vector_type(16)));

// ---------------- prep: weight casts + adjacency/mask bitpack + barrier init ----
struct CastArgs {
  const float* s[5];
  __bf16* d[5];
  int startblk[5];
};
__global__ __launch_bounds__(256) void prep_kernel(
    CastArgs a, const float* __restrict__ adj, unsigned long long* __restrict__ abits,
    const int* __restrict__ mask, unsigned long long* __restrict__ mbits,
    unsigned* __restrict__ bars) {
  int blk = blockIdx.x;
  int lane = threadIdx.x & 63;
  if (blk == 0 && threadIdx.x < 16) bars[threadIdx.x] = 0u;
  if (blk < 592) {
    int seg = 0;
#pragma unroll
    for (int i = 1; i < 5; i++) seg += (blk >= a.startblk[i]) ? 1 : 0;
    int i4 = (blk - a.startblk[seg]) * 256 + threadIdx.x;
    float4 v = ((const float4*)a.s[seg])[i4];
    bf4_t p = {(__bf16)v.x, (__bf16)v.y, (__bf16)v.z, (__bf16)v.w};
    ((bf4_t*)a.d[seg])[i4] = p;
  } else if (blk < 592 + 8192) {
    int g = ((blk - 592) * 4 + (threadIdx.x >> 6)) * 4;
    const float* p = adj + (size_t)g * 64 + lane;
    unsigned long long w0 = __ballot(p[0] != 0.0f);
    unsigned long long w1 = __ballot(p[64] != 0.0f);
    unsigned long long w2 = __ballot(p[128] != 0.0f);
    unsigned long long w3 = __ballot(p[192] != 0.0f);
    if (lane == 0) {
      abits[g] = w0; abits[g + 1] = w1; abits[g + 2] = w2; abits[g + 3] = w3;
    }
  } else {
    int g = (blk - 8784) * 4 + (threadIdx.x >> 6);
    int v = mask[g * 64 + lane];
    unsigned long long bal = __ballot(v != 0);
    if (lane == 0) mbits[g] = bal;
  }
}

// ---------------- persistent mega kernel ----------------
// 512 blocks x 512 threads, __launch_bounds__(512,4) (<=128 VGPR) + 68.6KB LDS
// -> exactly 2 blocks/CU, all 512 blocks co-resident (device empty at launch:
// serial stream). Software grid barrier (device-scope atomics + threadfence,
// one-shot flag per barrier, zeroed by prep) replaces 6 dispatch boundaries:
// F0 -> bar -> [attn(2 units/blk) -> bar -> layer -> bar]x3, head in last layer.
struct MegaArgs {
  const float* atom_embed; const float* cons_embed;
  const int* is_atom; const int* atom_id;
  const __bf16* wbin; const float* in_b;
  const __bf16* wbqkv; const float* qkv_b;
  const __bf16* wbout; const float* out_b;
  const __bf16* wbff1; const float* ff1_b;
  const __bf16* wbff2; const float* ff2_b;
  const float* ln1_g; const float* ln1_b;
  const float* ln2_g; const float* ln2_b;
  const float* sbias;
  const float* hg; const float* hbt; const float* hw; const float* hb;
  const int* root_idx; const int* mask;
  const unsigned* adjb; const unsigned* mskb;
  float* hA; float* hB;
  __bf16* Qb; __bf16* Kb; __bf16* Vt; __bf16* ob;
  unsigned* bars; float* out;
};

__global__ __launch_bounds__(512, 4) void mega_kernel(MegaArgs A) {
  extern __shared__ char smem[];
  const int blk = blockIdx.x;
  const int t = threadIdx.x;
  const int lane = t & 63, w = t >> 6;
  const int l15 = lane & 15, quad = lane >> 4;

  // LDS overlays (phases separated by barriers)
  auto Xs = (__bf16(*)[136])(smem);            // 16x136  (4352 B)
  auto Ws = (__bf16(*)[136])(smem + 4352);     // 128x136 (34816 B)
  auto Hs = (float(*)[132])(smem + 39168);     // 16x132  (8448 B)
  auto X2 = (__bf16(*)[136])(smem + 47616);    // 16x136  (4352 B)
  auto Fs = (__bf16(*)[520])(smem + 51968);    // 16x520  (16640 B) -> 68608
  auto Pbuf = (__bf16(*)[32][40])(smem);       // 8x32x40 (20480 B)
  auto Ored = (float(*)[32][17])(smem + 20480);// 8x32x17 (17408 B)
  auto Lred = (float(*)[32])(smem + 37888);    // 8x32    (1024 B)

  auto gridbar = [&](int bi) {
    __syncthreads();                            // drains vmcnt: stores in L2
    if (t == 0) {
      __threadfence();                          // release (agent scope: L2 wb)
      unsigned old = atomicAdd(&A.bars[bi * 2], 1u);
      if (old == NBLK - 1) {
        atomicAdd(&A.bars[bi * 2 + 1], 1u);
      } else {
        while (atomicAdd(&A.bars[bi * 2 + 1], 0u) == 0u)
          __builtin_amdgcn_s_sleep(2);
      }
      __threadfence();                          // acquire (invalidate stale)
    }
    __syncthreads();
  };

  auto do_ln = [&](const float* g_, const float* b_) {
    int r = t >> 5, c = t & 31;
    float4 v = *(const float4*)&Hs[r][c * 4];
    float s1 = v.x + v.y + v.z + v.w;
    float s2 = v.x * v.x + v.y * v.y + v.z * v.z + v.w * v.w;
#pragma unroll
    for (int m = 16; m >= 1; m >>= 1) {
      s1 += __shfl_xor(s1, m, 64);
      s2 += __shfl_xor(s2, m, 64);
    }
    float mean = s1 * (1.0f / ND);
    float var = s2 * (1.0f / ND) - mean * mean;
    float rstd = rsqrtf(var + LN_EPS);
    float4 gg = *(const float4*)&g_[c * 4];
    float4 bb = *(const float4*)&b_[c * 4];
    bf4_t p;
    p[0] = (__bf16)((v.x - mean) * rstd * gg.x + bb.x);
    p[1] = (__bf16)((v.y - mean) * rstd * gg.y + bb.y);
    p[2] = (__bf16)((v.z - mean) * rstd * gg.z + bb.z);
    p[3] = (__bf16)((v.w - mean) * rstd * gg.w + bb.w);
    *(bf4_t*)&X2[r][c * 4] = p;
  };

  // ================= phase F0: embed + in-proj + LN1[0] + qkv[0] =============
  {
    int m0 = (blk >> 1) * 16;
    int g = blk & 1;
    const int NC2 = (g == 0) ? 2 : 1;
    const int T = 1 + NC2;
    {
      int r = t >> 5, c = t & 31;
      int row = m0 + r;
      int id = A.atom_id[row];
      id = id < 0 ? 0 : (id > NV - 1 ? NV - 1 : id);
      const float* src = A.is_atom[row] ? (A.atom_embed + (size_t)id * ND) : A.cons_embed;
      float4 v = *(const float4*)&src[c * 4];
      bf4_t p = {(__bf16)v.x, (__bf16)v.y, (__bf16)v.z, (__bf16)v.w};
      *(bf4_t*)&Xs[r][c * 4] = p;
    }
    bf8_t wreg[4];
    auto issue = [&](int i) {
      const __bf16* base;
      int rowoff;
      if (i == 0) { base = A.wbin; rowoff = 0; }
      else { int nc = (g == 0) ? (i - 1) : 2; base = A.wbqkv; rowoff = nc * 128; }
#pragma unroll
      for (int jj = 0; jj < 4; jj++) {
        int c = t + jj * 512;
        wreg[jj] = *(const bf8_t*)&base[(size_t)(rowoff + (c >> 4)) * 128 + (c & 15) * 8];
      }
    };
    issue(0);
    for (int i = 0; i < T; i++) {
      if (i) __syncthreads();
#pragma unroll
      for (int jj = 0; jj < 4; jj++) {
        int c = t + jj * 512;
        *(bf8_t*)&Ws[c >> 4][(c & 15) * 8] = wreg[jj];
      }
      __syncthreads();
      if (i + 1 < T) issue(i + 1);
      if (i == 0) {
        f4x a1 = {0.f, 0.f, 0.f, 0.f};
#pragma unroll
        for (int kk = 0; kk < 4; kk++) {
          bf8_t a = *(const bf8_t*)&Xs[l15][kk * 32 + quad * 8];
          bf8_t b = *(const bf8_t*)&Ws[w * 16 + l15][kk * 32 + quad * 8];
          a1 = __builtin_amdgcn_mfma_f32_16x16x32_bf16(a, b, a1, 0, 0, 0);
        }
        int n = w * 16 + l15;
        float bv = A.in_b[n];
#pragma unroll
        for (int r = 0; r < 4; r++) {
          int m = quad * 4 + r;
          float v = a1[r] + bv;
          if (g == 0) A.hA[(size_t)(m0 + m) * ND + n] = v;
          Hs[m][n] = v;
        }
        __syncthreads();
        do_ln(A.ln1_g, A.ln1_b);
      } else {
        int nc = (g == 0) ? (i - 1) : 2;
        f4x a2 = {0.f, 0.f, 0.f, 0.f};
#pragma unroll
        for (int kk = 0; kk < 4; kk++) {
          bf8_t a = *(const bf8_t*)&X2[l15][kk * 32 + quad * 8];
          bf8_t b = *(const bf8_t*)&Ws[w * 16 + l15][kk * 32 + quad * 8];
          a2 = __builtin_amdgcn_mfma_f32_16x16x32_bf16(a, b, a2, 0, 0, 0);
        }
        int n = nc * 128 + w * 16 + l15;
        float bv = A.qkv_b[n];
#pragma unroll
        for (int r = 0; r < 4; r++) {
          int m = m0 + quad * 4 + r;
          float v = a2[r] + bv;
          if (n < ND) A.Qb[(size_t)m * ND + n] = (__bf16)(v * QSCALE);
          else if (n < 2 * ND) A.Kb[(size_t)m * ND + n - ND] = (__bf16)v;
          else {
            int c2 = n - 2 * ND, hh = c2 >> 4, d0 = c2 & 15;
            int bb2 = m >> 11, nn = m & 2047;
            A.Vt[((size_t)((bb2 * NH + hh) * NDH + d0)) * NN + nn] = (__bf16)v;
          }
        }
      }
    }
  }
  gridbar(0);

  for (int layer = 0; layer < NL; layer++) {
    // ================= attention: 2 units per block =================
    float esb = __expf(A.sbias[layer]);
    for (int u2 = 0; u2 < 2; u2++) {
      int u = blk + u2 * NBLK;
      int b = u >> 9, hh = (u >> 6) & 7, q0 = (u & 63) * 32;
      int l31 = lane & 31, hi = lane >> 5;
      const int bN = b * NN;
      const int kw0 = w * 256;

      bf8_t Qf = *(const bf8_t*)(A.Qb + (size_t)(bN + q0 + l31) * ND + hh * NDH + hi * 8);
      int q = q0 + l31;
      int mq = A.mask[bN + q];
      const unsigned* adjp = A.adjb + (size_t)(bN + q) * (NN / 32) + (kw0 >> 5);
      const unsigned* mbp = A.mskb + (bN + kw0) / 32;
      const __bf16* kp = A.Kb + (size_t)(bN + kw0 + l31) * ND + hh * NDH + hi * 8;
      const __bf16* vp = A.Vt + (size_t)((b * NH + hh) * NDH + l15) * NN + kw0 + quad * 8;

      int dq = q - kw0;
      int tsel = dq >> 5;
      unsigned selfw = 1u << (dq & 31);
      int sh4 = hi * 4;

      f4x Olo = {0.f, 0.f, 0.f, 0.f}, Ohi = {0.f, 0.f, 0.f, 0.f};
      float ls = 0.f;

      bf8_t Kf = *(const bf8_t*)kp;
      bf8_t Vf = *(const bf8_t*)vp;
      unsigned aw = adjp[0];
      unsigned mkw = mbp[0];

      for (int tt = 0; tt < 8; tt++) {
        bf8_t Kn = Kf, Vn = Vf;
        unsigned awn = aw, mkn = mkw;
        if (tt < 7) {
          kp += 32 * ND;
          Kn = *(const bf8_t*)kp;
          Vn = *(const bf8_t*)(vp + (tt + 1) * 32);
          awn = adjp[tt + 1];
          mkn = mbp[tt + 1];
        }
        f16x S = {0.f, 0.f, 0.f, 0.f, 0.f, 0.f, 0.f, 0.f,
                  0.f, 0.f, 0.f, 0.f, 0.f, 0.f, 0.f, 0.f};
        S = __builtin_amdgcn_mfma_f32_32x32x16_bf16(Kf, Qf, S, 0, 0, 0);
        unsigned okw = mq ? mkw : ((tt == tsel) ? selfw : 0u);
        unsigned wa = (aw & okw) >> sh4;
        unsigned okh = okw >> sh4;
#pragma unroll
        for (int gg = 0; gg < 4; gg++) {
          bf4_t pk;
#pragma unroll
          for (int r = 0; r < 4; r++) {
            int c = gg * 8 + r;
            float e = __builtin_amdgcn_exp2f(S[gg * 4 + r]);
            float wgt = ((wa >> c) & 1) ? esb : (((okh >> c) & 1) ? 1.0f : 0.0f);
            float p = e * wgt;
            ls += p;
            pk[r] = (__bf16)p;
          }
          *(bf4_t*)&Pbuf[w][l31][sh4 + gg * 8] = pk;
        }
        asm volatile("s_waitcnt lgkmcnt(0)" ::: "memory");
        bf8_t Plo = *(const bf8_t*)&Pbuf[w][l15][quad * 8];
        bf8_t Phi = *(const bf8_t*)&Pbuf[w][16 + l15][quad * 8];
        Olo = __builtin_amdgcn_mfma_f32_16x16x32_bf16(Plo, Vf, Olo, 0, 0, 0);
        Ohi = __builtin_amdgcn_mfma_f32_16x16x32_bf16(Phi, Vf, Ohi, 0, 0, 0);
        Kf = Kn; Vf = Vn; aw = awn; mkw = mkn;
      }

      ls += __shfl_xor(ls, 32, 64);
      if (hi == 0) Lred[w][l31] = ls;
#pragma unroll
      for (int r = 0; r < 4; r++) {
        Ored[w][quad * 4 + r][l15] = Olo[r];
        Ored[w][16 + quad * 4 + r][l15] = Ohi[r];
      }
      __syncthreads();
      int row = t >> 4, col = t & 15;
      float s = 0.f, L = 0.f;
#pragma unroll
      for (int p = 0; p < 8; p++) {
        s += Ored[p][row][col];
        L += Lred[p][row];
      }
      A.ob[(size_t)(bN + q0 + row) * ND + hh * NDH + col] = (__bf16)(s / L);
      __syncthreads();   // protect smem reuse by the next unit
    }
    gridbar(1 + 2 * layer);

    // ================= layer segment =================
    {
      int m0 = (blk >> 1) * 16;
      int g = blk & 1;
      const int last = (layer == NL - 1);
      const float* Hin = (layer & 1) ? A.hB : A.hA;
      float* Hout = (layer & 1) ? A.hA : A.hB;
      const __bf16* Wout = A.wbout + (size_t)layer * ND * ND;
      const float* bout = A.out_b + layer * ND;
      const __bf16* Wff1 = A.wbff1 + (size_t)layer * 512 * ND;
      const float* bff1 = A.ff1_b + layer * 512;
      const __bf16* Wff2 = A.wbff2 + (size_t)layer * ND * 512;
      const float* bff2 = A.ff2_b + layer * ND;
      const __bf16* Wqkv = A.wbqkv + (size_t)(layer + 1) * 384 * ND;
      const float* bqkv = A.qkv_b + (layer + 1) * 384;
      const float* ln1g = A.ln1_g + (layer + 1) * ND;
      const float* ln1b = A.ln1_b + (layer + 1) * ND;
      const int NQ = last ? 0 : (g == 0 ? 2 : 1);
      const int T = 9 + NQ;

      {
        int r = t >> 5, c = t & 31;
        *(bf4_t*)&Xs[r][c * 4] = *(const bf4_t*)&A.ob[(size_t)(m0 + r) * ND + c * 4];
      }
      bf8_t wreg[4];
      auto issue = [&](int i) {
        const __bf16* base;
        int stride, rowoff, coloff;
        if (i == 0)     { base = Wout; stride = 128; rowoff = 0;             coloff = 0; }
        else if (i < 5) { base = Wff1; stride = 128; rowoff = (i - 1) * 128; coloff = 0; }
        else if (i < 9) { base = Wff2; stride = 512; rowoff = 0;             coloff = (i - 5) * 128; }
        else            { int nc = (g == 0) ? (i - 9) : 2;
                          base = Wqkv; stride = 128; rowoff = nc * 128;      coloff = 0; }
#pragma unroll
        for (int jj = 0; jj < 4; jj++) {
          int c = t + jj * 512;
          wreg[jj] = *(const bf8_t*)&base[(size_t)(rowoff + (c >> 4)) * stride + coloff + (c & 15) * 8];
        }
      };
      issue(0);

      f4x acc2 = {0.f, 0.f, 0.f, 0.f};
      for (int i = 0; i < T; i++) {
        if (i) __syncthreads();
#pragma unroll
        for (int jj = 0; jj < 4; jj++) {
          int c = t + jj * 512;
          *(bf8_t*)&Ws[c >> 4][(c & 15) * 8] = wreg[jj];
        }
        __syncthreads();
        if (i + 1 < T) issue(i + 1);
        if (i == 0) {
          f4x a1 = {0.f, 0.f, 0.f, 0.f};
#pragma unroll
          for (int kk = 0; kk < 4; kk++) {
            bf8_t a = *(const bf8_t*)&Xs[l15][kk * 32 + quad * 8];
            bf8_t b = *(const bf8_t*)&Ws[w * 16 + l15][kk * 32 + quad * 8];
            a1 = __builtin_amdgcn_mfma_f32_16x16x32_bf16(a, b, a1, 0, 0, 0);
          }
          int n = w * 16 + l15;
          float bv = bout[n];
#pragma unroll
          for (int r = 0; r < 4; r++) {
            int m = quad * 4 + r;
            Hs[m][n] = a1[r] + bv + Hin[(size_t)(m0 + m) * ND + n];
          }
          __syncthreads();
          do_ln(A.ln2_g + layer * ND, A.ln2_b + layer * ND);
        } else if (i < 5) {
          int c = i - 1;
          f4x a1 = {0.f, 0.f, 0.f, 0.f};
#pragma unroll
          for (int kk = 0; kk < 4; kk++) {
            bf8_t a = *(const bf8_t*)&X2[l15][kk * 32 + quad * 8];
            bf8_t b = *(const bf8_t*)&Ws[w * 16 + l15][kk * 32 + quad * 8];
            a1 = __builtin_amdgcn_mfma_f32_16x16x32_bf16(a, b, a1, 0, 0, 0);
          }
          int n = w * 16 + l15;
          float bv = bff1[c * 128 + n];
#pragma unroll
          for (int r = 0; r < 4; r++) {
            float v = a1[r] + bv;
            v = 0.5f * v * (1.0f + erff(v * 0.70710678118f));
            Fs[quad * 4 + r][c * 128 + n] = (__bf16)v;
          }
        } else if (i < 9) {
          int j = i - 5;
#pragma unroll
          for (int kk = 0; kk < 4; kk++) {
            bf8_t a = *(const bf8_t*)&Fs[l15][j * 128 + kk * 32 + quad * 8];
            bf8_t b = *(const bf8_t*)&Ws[w * 16 + l15][kk * 32 + quad * 8];
            acc2 = __builtin_amdgcn_mfma_f32_16x16x32_bf16(a, b, acc2, 0, 0, 0);
          }
          if (j == 3) {
            int n = w * 16 + l15;
            float bv = bff2[n];
#pragma unroll
            for (int r = 0; r < 4; r++) {
              int m = quad * 4 + r;
              float v = acc2[r] + bv + Hs[m][n];
              Hs[m][n] = v;
              if (g == 0) Hout[(size_t)(m0 + m) * ND + n] = v;
            }
            __syncthreads();
            if (!last) do_ln(ln1g, ln1b);
          }
        } else {
          int nc = (g == 0) ? (i - 9) : 2;
          f4x a2 = {0.f, 0.f, 0.f, 0.f};
#pragma unroll
          for (int kk = 0; kk < 4; kk++) {
            bf8_t a = *(const bf8_t*)&X2[l15][kk * 32 + quad * 8];
            bf8_t b = *(const bf8_t*)&Ws[w * 16 + l15][kk * 32 + quad * 8];
            a2 = __builtin_amdgcn_mfma_f32_16x16x32_bf16(a, b, a2, 0, 0, 0);
          }
          int n = nc * 128 + w * 16 + l15;
          float bv = bqkv[n];
#pragma unroll
          for (int r = 0; r < 4; r++) {
            int m = m0 + quad * 4 + r;
            float v = a2[r] + bv;
            if (n < ND) A.Qb[(size_t)m * ND + n] = (__bf16)(v * QSCALE);
            else if (n < 2 * ND) A.Kb[(size_t)m * ND + n - ND] = (__bf16)v;
            else {
              int c2 = n - 2 * ND, hh = c2 >> 4, d0 = c2 & 15;
              int bb2 = m >> 11, nn = m & 2047;
              A.Vt[((size_t)((bb2 * NH + hh) * NDH + d0)) * NN + nn] = (__bf16)v;
            }
          }
        }
      }

      if (last && g == 0 && w < NB) {
        int rt = A.root_idx[w];
        int rglob = w * NN + rt;
        if (rglob >= m0 && rglob < m0 + 16) {
          int r = rglob - m0;
          float v0 = Hs[r][2 * lane], v1 = Hs[r][2 * lane + 1];
          float s1 = v0 + v1, s2 = v0 * v0 + v1 * v1;
#pragma unroll
          for (int m = 32; m >= 1; m >>= 1) {
            s1 += __shfl_xor(s1, m, 64);
            s2 += __shfl_xor(s2, m, 64);
          }
          float mean = s1 * (1.0f / ND);
          float var = s2 * (1.0f / ND) - mean * mean;
          float rstd = rsqrtf(var + LN_EPS);
          float p0 = (v0 - mean) * rstd * A.hg[2 * lane] + A.hbt[2 * lane];
          float p1 = (v1 - mean) * rstd * A.hg[2 * lane + 1] + A.hbt[2 * lane + 1];
          float part = p0 * A.hw[2 * lane] + p1 * A.hw[2 * lane + 1];
#pragma unroll
          for (int m = 32; m >= 1; m >>= 1) part += __shfl_xor(part, m, 64);
          if (lane == 0) A.out[w] = part + A.hb[0];
        }
      }
    }
    if (layer < NL - 1) gridbar(2 + 2 * layer);
  }
}

extern "C" void kernel_launch(void* const* d_in, const int* in_sizes, int n_in,
                              void* d_out, int out_size, void* d_ws, size_t ws_size,
                              hipStream_t stream) {
  const float* atom_embed = (const float*)d_in[0];
  const float* cons_embed = (const float*)d_in[1];
  const float* in_w  = (const float*)d_in[2];
  const float* in_b  = (const float*)d_in[3];
  const float* qkv_w = (const float*)d_in[4];
  const float* qkv_b = (const float*)d_in[5];
  const float* out_w = (const float*)d_in[6];
  const float* out_b = (const float*)d_in[7];
  const float* ln1_g = (const float*)d_in[8];
  const float* ln1_b = (const float*)d_in[9];
  const float* ln2_g = (const float*)d_in[10];
  const float* ln2_b = (const float*)d_in[11];
  const float* ff1_w = (const float*)d_in[12];
  const float* ff1_b = (const float*)d_in[13];
  const float* ff2_w = (const float*)d_in[14];
  const float* ff2_b = (const float*)d_in[15];
  const float* sbias = (const float*)d_in[16];
  const float* hg    = (const float*)d_in[17];
  const float* hbt   = (const float*)d_in[18];
  const float* hw    = (const float*)d_in[19];
  const float* hb    = (const float*)d_in[20];
  const float* adj   = (const float*)d_in[21];
  const int* is_atom = (const int*)d_in[22];
  const int* atom_id = (const int*)d_in[23];
  const int* mask    = (const int*)d_in[24];
  const int* root_idx= (const int*)d_in[25];
  float* out = (float*)d_out;

  const int MR = NB * NN;  // 4096 rows
  float* hA = (float*)d_ws;
  float* hB = hA + MR * ND;
  __bf16* Qb   = (__bf16*)(hB + MR * ND);
  __bf16* Kb   = Qb + MR * ND;
  __bf16* Vt   = Kb + MR * ND;
  __bf16* wbin = Vt + MR * ND;
  __bf16* wbqkv= wbin + ND * ND;
  __bf16* wbout= wbqkv + NL * 384 * ND;
  __bf16* wbff1= wbout + NL * ND * ND;
  __bf16* wbff2= wbff1 + NL * 512 * ND;
  unsigned int* adjb = (unsigned int*)(wbff2 + NL * ND * 512);
  unsigned int* mskb = adjb + NB * NN * NN / 32;
  __bf16* ob = (__bf16*)(mskb + 128);
  unsigned* bars = (unsigned*)(ob + MR * ND);

  CastArgs ca;
  ca.s[0] = in_w;  ca.d[0] = wbin;  ca.startblk[0] = 0;
  ca.s[1] = qkv_w; ca.d[1] = wbqkv; ca.startblk[1] = 16;
  ca.s[2] = out_w; ca.d[2] = wbout; ca.startblk[2] = 160;
  ca.s[3] = ff1_w; ca.d[3] = wbff1; ca.startblk[3] = 208;
  ca.s[4] = ff2_w; ca.d[4] = wbff2; ca.startblk[4] = 400;
  prep_kernel<<<8800, 256, 0, stream>>>(ca, adj, (unsigned long long*)adjb,
                                        mask, (unsigned long long*)mskb, bars);

  MegaArgs A;
  A.atom_embed = atom_embed; A.cons_embed = cons_embed;
  A.is_atom = is_atom; A.atom_id = atom_id;
  A.wbin = wbin; A.in_b = in_b;
  A.wbqkv = wbqkv; A.qkv_b = qkv_b;
  A.wbout = wbout; A.out_b = out_b;
  A.wbff1 = wbff1; A.ff1_b = ff1_b;
  A.wbff2 = wbff2; A.ff2_b = ff2_b;
  A.ln1_g = ln1_g; A.ln1_b = ln1_b;
  A.ln2_g = ln2_g; A.ln2_b = ln2_b;
  A.sbias = sbias;
  A.hg = hg; A.hbt = hbt; A.hw = hw; A.hb = hb;
  A.root_idx = root_idx; A.mask = mask;
  A.adjb = adjb; A.mskb = mskb;
  A.hA = hA; A.hB = hB;
  A.Qb = Qb; A.Kb = Kb; A.Vt = Vt; A.ob = ob;
  A.bars = bars; A.out = out;
  mega_kernel<<<NBLK, 512, SMEM_BYTES, stream>>>(A);
}

// Round 13
// 269.121 us; speedup vs baseline: 2.1397x; 2.1397x over previous
//
#include <hip/hip_runtime.h>
#include <cmath>

#define NB 2
#define NN 2048
#define ND 128
#define NH 8
#define NL 3
#define NV 32
#define NDH 16
#define LN_EPS 1e-5f
/* ATT_SCALE(0.25) * log2(e), folded into Q at qkv-pack time so the attention
   inner loop is a raw exp2 per score. */
#define QSCALE 0.36067376022224085f

typedef __bf16 bf8_t __attribute__((ext_vector_type(8)));
typedef __bf16 bf4_t __attribute__((ext_vector_type(4)));
typedef float f4x __attribute__((ext_vector_type(4)));
typedef float f16x __attribute__((ext_vector_type(16)));

// ---------------- entry kernel: fused0 + weight casts + adj/mask bitpack ----
// One dispatch, three block roles (no intra-dispatch dependencies):
//   [0,512):     fused0 = embed + in-proj + LN1[0] + qkv[0]; stages its own
//                weights from fp32 (cvt in staging) so it needs no pre-cast.
//   [512,578):   cast layer weights (qkv[1:], out, ff1, ff2) -> bf16 ws bufs
//                (consumed only by later dispatches).
//   [578,1602):  adjacency bitpack.  [1602]: mask bitpack.
struct EntryArgs {
  const float* atom_embed; const float* cons_embed;
  const int* is_atom; const int* atom_id;
  const float* in_w; const float* in_b;
  const float* qkv_w; const float* qkv_b;
  const float* ln1_g; const float* ln1_b;
  float* hA;
  __bf16* Qb; __bf16* Kb; __bf16* Vt;
  // cast segments
  const float* out_w; const float* ff1_w; const float* ff2_w;
  __bf16* wbqkv; __bf16* wbout; __bf16* wbff1; __bf16* wbff2;
  // bitpack
  const float* adj; unsigned long long* abits;
  const int* mask; unsigned long long* mbits;
};

__global__ __launch_bounds__(512) void entry_kernel(EntryArgs A) {
  __shared__ __bf16 Xs[16][136];
  __shared__ __bf16 Ws[128][136];
  __shared__ float Hs[16][132];
  __shared__ __bf16 X2[16][136];
  const int blk = blockIdx.x;
  const int t = threadIdx.x;
  const int lane = t & 63, w = t >> 6;
  const int l15 = lane & 15, quad = lane >> 4;

  if (blk >= 512) {
    if (blk < 578) {
      // ---- weight casts: 2048 float4-groups per block ----
      int bi = blk - 512;
#pragma unroll
      for (int u = 0; u < 4; u++) {
        int i4 = bi * 2048 + u * 512 + t;
        if (i4 >= 135168) break;
        const float* s;
        __bf16* d;
        if (i4 < 24576)      { int j = i4;          s = A.qkv_w + 49152 + j * 4; d = A.wbqkv + 49152 + j * 4; }
        else if (i4 < 36864) { int j = i4 - 24576;  s = A.out_w + j * 4;         d = A.wbout + j * 4; }
        else if (i4 < 86016) { int j = i4 - 36864;  s = A.ff1_w + j * 4;         d = A.wbff1 + j * 4; }
        else                 { int j = i4 - 86016;  s = A.ff2_w + j * 4;         d = A.wbff2 + j * 4; }
        float4 v = *(const float4*)s;
        bf4_t p = {(__bf16)v.x, (__bf16)v.y, (__bf16)v.z, (__bf16)v.w};
        *(bf4_t*)d = p;
      }
    } else if (blk < 1602) {
      // ---- adjacency bitpack: 8 waves x 16 groups of 64 ----
      int bi = blk - 578;
#pragma unroll
      for (int k = 0; k < 16; k++) {
        int g = (bi * 8 + w) * 16 + k;
        unsigned long long bal = __ballot(A.adj[(size_t)g * 64 + lane] != 0.0f);
        if (lane == 0) A.abits[g] = bal;
      }
    } else {
      // ---- mask bitpack: 64 groups ----
#pragma unroll
      for (int k = 0; k < 8; k++) {
        int g = w * 8 + k;
        unsigned long long bal = __ballot(A.mask[g * 64 + lane] != 0);
        if (lane == 0) A.mbits[g] = bal;
      }
    }
    return;
  }

  // ---- fused0 ----
  int m0 = (blk >> 1) * 16;
  int g = blk & 1;
  const int NC2 = (g == 0) ? 2 : 1;
  const int T = 1 + NC2;
  {
    int r = t >> 5, c = t & 31;
    int row = m0 + r;
    int id = A.atom_id[row];
    id = id < 0 ? 0 : (id > NV - 1 ? NV - 1 : id);
    const float* src = A.is_atom[row] ? (A.atom_embed + (size_t)id * ND) : A.cons_embed;
    float4 v = *(const float4*)&src[c * 4];
    bf4_t p = {(__bf16)v.x, (__bf16)v.y, (__bf16)v.z, (__bf16)v.w};
    *(bf4_t*)&Xs[r][c * 4] = p;
  }

  float4 wf[8];                       // fp32 weight staging (cvt to bf16 on store)
  auto issue = [&](int i) {
    const float* base;
    int rowoff;
    if (i == 0) { base = A.in_w; rowoff = 0; }
    else { int nc = (g == 0) ? (i - 1) : 2; base = A.qkv_w; rowoff = nc * 128; }
#pragma unroll
    for (int jj = 0; jj < 4; jj++) {
      int c = t + jj * 512;
      const float* p = &base[(size_t)(rowoff + (c >> 4)) * 128 + (c & 15) * 8];
      wf[jj * 2] = *(const float4*)p;
      wf[jj * 2 + 1] = *(const float4*)(p + 4);
    }
  };
  issue(0);

  for (int i = 0; i < T; i++) {
    if (i) __syncthreads();
#pragma unroll
    for (int jj = 0; jj < 4; jj++) {
      int c = t + jj * 512;
      bf8_t r;
      float4 a = wf[jj * 2], b = wf[jj * 2 + 1];
      r[0] = (__bf16)a.x; r[1] = (__bf16)a.y; r[2] = (__bf16)a.z; r[3] = (__bf16)a.w;
      r[4] = (__bf16)b.x; r[5] = (__bf16)b.y; r[6] = (__bf16)b.z; r[7] = (__bf16)b.w;
      *(bf8_t*)&Ws[c >> 4][(c & 15) * 8] = r;
    }
    __syncthreads();
    if (i + 1 < T) issue(i + 1);
    if (i == 0) {
      f4x a1 = {0.f, 0.f, 0.f, 0.f};
#pragma unroll
      for (int kk = 0; kk < 4; kk++) {
        bf8_t a = *(const bf8_t*)&Xs[l15][kk * 32 + quad * 8];
        bf8_t b = *(const bf8_t*)&Ws[w * 16 + l15][kk * 32 + quad * 8];
        a1 = __builtin_amdgcn_mfma_f32_16x16x32_bf16(a, b, a1, 0, 0, 0);
      }
      int n = w * 16 + l15;
      float bv = A.in_b[n];
#pragma unroll
      for (int r = 0; r < 4; r++) {
        int m = quad * 4 + r;
        float v = a1[r] + bv;
        if (g == 0) A.hA[(size_t)(m0 + m) * ND + n] = v;
        Hs[m][n] = v;
      }
      __syncthreads();
      {
        int r = t >> 5, c = t & 31;
        float4 v = *(const float4*)&Hs[r][c * 4];
        float s1 = v.x + v.y + v.z + v.w;
        float s2 = v.x * v.x + v.y * v.y + v.z * v.z + v.w * v.w;
#pragma unroll
        for (int m = 16; m >= 1; m >>= 1) {
          s1 += __shfl_xor(s1, m, 64);
          s2 += __shfl_xor(s2, m, 64);
        }
        float mean = s1 * (1.0f / ND);
        float var = s2 * (1.0f / ND) - mean * mean;
        float rstd = rsqrtf(var + LN_EPS);
        float4 gg = *(const float4*)&A.ln1_g[c * 4];
        float4 bb = *(const float4*)&A.ln1_b[c * 4];
        bf4_t p;
        p[0] = (__bf16)((v.x - mean) * rstd * gg.x + bb.x);
        p[1] = (__bf16)((v.y - mean) * rstd * gg.y + bb.y);
        p[2] = (__bf16)((v.z - mean) * rstd * gg.z + bb.z);
        p[3] = (__bf16)((v.w - mean) * rstd * gg.w + bb.w);
        *(bf4_t*)&X2[r][c * 4] = p;
      }
    } else {
      int nc = (g == 0) ? (i - 1) : 2;
      f4x a2 = {0.f, 0.f, 0.f, 0.f};
#pragma unroll
      for (int kk = 0; kk < 4; kk++) {
        bf8_t a = *(const bf8_t*)&X2[l15][kk * 32 + quad * 8];
        bf8_t b = *(const bf8_t*)&Ws[w * 16 + l15][kk * 32 + quad * 8];
        a2 = __builtin_amdgcn_mfma_f32_16x16x32_bf16(a, b, a2, 0, 0, 0);
      }
      int n = nc * 128 + w * 16 + l15;
      float bv = A.qkv_b[n];
#pragma unroll
      for (int r = 0; r < 4; r++) {
        int m = m0 + quad * 4 + r;
        float v = a2[r] + bv;
        if (n < ND) A.Qb[(size_t)m * ND + n] = (__bf16)(v * QSCALE);
        else if (n < 2 * ND) A.Kb[(size_t)m * ND + n - ND] = (__bf16)v;
        else {
          int c2 = n - 2 * ND, hh = c2 >> 4, d0 = c2 & 15;
          int bb2 = m >> 11, nn = m & 2047;
          A.Vt[((size_t)((bb2 * NH + hh) * NDH + d0)) * NN + nn] = (__bf16)v;
        }
      }
    }
  }
}

// ---------------- per-layer mega kernel (R11 structure, unchanged) ----------
template <int LAST>
__global__ __launch_bounds__(512) void layer_kernel(
    const __bf16* __restrict__ Ob,
    const __bf16* __restrict__ Wout, const float* __restrict__ bout,
    const float* __restrict__ Hin, float* __restrict__ Hout,
    const float* __restrict__ ln2g, const float* __restrict__ ln2b,
    const __bf16* __restrict__ Wff1, const float* __restrict__ bff1,
    const __bf16* __restrict__ Wff2, const float* __restrict__ bff2,
    const float* __restrict__ ln1g, const float* __restrict__ ln1b,
    const __bf16* __restrict__ Wqkv, const float* __restrict__ bqkv,
    __bf16* __restrict__ Qb, __bf16* __restrict__ Kb, __bf16* __restrict__ Vt,
    const int* __restrict__ root_idx, const float* __restrict__ hg,
    const float* __restrict__ hbt, const float* __restrict__ hwp,
    const float* __restrict__ hbp, float* __restrict__ outp) {
  __shared__ __bf16 Xs[16][136];
  __shared__ __bf16 Ws[128][136];
  __shared__ float Hs[16][132];
  __shared__ __bf16 X2[16][136];
  __shared__ __bf16 Fs[16][520];
  int m0 = blockIdx.x * 16;
  int g = blockIdx.y;
  int t = threadIdx.x;
  int lane = t & 63, w = t >> 6;
  int l15 = lane & 15, quad = lane >> 4;
  const int NQ = LAST ? 0 : (g == 0 ? 2 : 1);
  const int T = 9 + NQ;

  {
    int r = t >> 5, c = t & 31;
    *(bf4_t*)&Xs[r][c * 4] = *(const bf4_t*)&Ob[(size_t)(m0 + r) * ND + c * 4];
  }

  bf8_t wreg[4];
  auto issue = [&](int i) {
    const __bf16* base;
    int stride, rowoff, coloff;
    if (i == 0)     { base = Wout; stride = 128; rowoff = 0;             coloff = 0; }
    else if (i < 5) { base = Wff1; stride = 128; rowoff = (i - 1) * 128; coloff = 0; }
    else if (i < 9) { base = Wff2; stride = 512; rowoff = 0;             coloff = (i - 5) * 128; }
    else            { int nc = (g == 0) ? (i - 9) : 2;
                      base = Wqkv; stride = 128; rowoff = nc * 128;      coloff = 0; }
#pragma unroll
    for (int jj = 0; jj < 4; jj++) {
      int c = t + jj * 512;
      wreg[jj] = *(const bf8_t*)&base[(size_t)(rowoff + (c >> 4)) * stride + coloff + (c & 15) * 8];
    }
  };
  issue(0);

  auto do_ln = [&](const float* g_, const float* b_) {
    int r = t >> 5, c = t & 31;
    float4 v = *(const float4*)&Hs[r][c * 4];
    float s1 = v.x + v.y + v.z + v.w;
    float s2 = v.x * v.x + v.y * v.y + v.z * v.z + v.w * v.w;
#pragma unroll
    for (int m = 16; m >= 1; m >>= 1) {
      s1 += __shfl_xor(s1, m, 64);
      s2 += __shfl_xor(s2, m, 64);
    }
    float mean = s1 * (1.0f / ND);
    float var = s2 * (1.0f / ND) - mean * mean;
    float rstd = rsqrtf(var + LN_EPS);
    float4 gg = *(const float4*)&g_[c * 4];
    float4 bb = *(const float4*)&b_[c * 4];
    bf4_t p;
    p[0] = (__bf16)((v.x - mean) * rstd * gg.x + bb.x);
    p[1] = (__bf16)((v.y - mean) * rstd * gg.y + bb.y);
    p[2] = (__bf16)((v.z - mean) * rstd * gg.z + bb.z);
    p[3] = (__bf16)((v.w - mean) * rstd * gg.w + bb.w);
    *(bf4_t*)&X2[r][c * 4] = p;
  };

  f4x acc2 = {0.f, 0.f, 0.f, 0.f};
  for (int i = 0; i < T; i++) {
    if (i) __syncthreads();
#pragma unroll
    for (int jj = 0; jj < 4; jj++) {
      int c = t + jj * 512;
      *(bf8_t*)&Ws[c >> 4][(c & 15) * 8] = wreg[jj];
    }
    __syncthreads();
    if (i + 1 < T) issue(i + 1);
    if (i == 0) {
      f4x a1 = {0.f, 0.f, 0.f, 0.f};
#pragma unroll
      for (int kk = 0; kk < 4; kk++) {
        bf8_t a = *(const bf8_t*)&Xs[l15][kk * 32 + quad * 8];
        bf8_t b = *(const bf8_t*)&Ws[w * 16 + l15][kk * 32 + quad * 8];
        a1 = __builtin_amdgcn_mfma_f32_16x16x32_bf16(a, b, a1, 0, 0, 0);
      }
      int n = w * 16 + l15;
      float bv = bout[n];
#pragma unroll
      for (int r = 0; r < 4; r++) {
        int m = quad * 4 + r;
        Hs[m][n] = a1[r] + bv + Hin[(size_t)(m0 + m) * ND + n];
      }
      __syncthreads();
      do_ln(ln2g, ln2b);
    } else if (i < 5) {
      int c = i - 1;
      f4x a1 = {0.f, 0.f, 0.f, 0.f};
#pragma unroll
      for (int kk = 0; kk < 4; kk++) {
        bf8_t a = *(const bf8_t*)&X2[l15][kk * 32 + quad * 8];
        bf8_t b = *(const bf8_t*)&Ws[w * 16 + l15][kk * 32 + quad * 8];
        a1 = __builtin_amdgcn_mfma_f32_16x16x32_bf16(a, b, a1, 0, 0, 0);
      }
      int n = w * 16 + l15;
      float bv = bff1[c * 128 + n];
#pragma unroll
      for (int r = 0; r < 4; r++) {
        float v = a1[r] + bv;
        v = 0.5f * v * (1.0f + erff(v * 0.70710678118f));
        Fs[quad * 4 + r][c * 128 + n] = (__bf16)v;
      }
    } else if (i < 9) {
      int j = i - 5;
#pragma unroll
      for (int kk = 0; kk < 4; kk++) {
        bf8_t a = *(const bf8_t*)&Fs[l15][j * 128 + kk * 32 + quad * 8];
        bf8_t b = *(const bf8_t*)&Ws[w * 16 + l15][kk * 32 + quad * 8];
        acc2 = __builtin_amdgcn_mfma_f32_16x16x32_bf16(a, b, acc2, 0, 0, 0);
      }
      if (j == 3) {
        int n = w * 16 + l15;
        float bv = bff2[n];
#pragma unroll
        for (int r = 0; r < 4; r++) {
          int m = quad * 4 + r;
          float v = acc2[r] + bv + Hs[m][n];
          Hs[m][n] = v;
          if (g == 0) Hout[(size_t)(m0 + m) * ND + n] = v;
        }
        __syncthreads();
        if constexpr (!LAST) do_ln(ln1g, ln1b);
      }
    } else {
      int nc = (g == 0) ? (i - 9) : 2;
      f4x a2 = {0.f, 0.f, 0.f, 0.f};
#pragma unroll
      for (int kk = 0; kk < 4; kk++) {
        bf8_t a = *(const bf8_t*)&X2[l15][kk * 32 + quad * 8];
        bf8_t b = *(const bf8_t*)&Ws[w * 16 + l15][kk * 32 + quad * 8];
        a2 = __builtin_amdgcn_mfma_f32_16x16x32_bf16(a, b, a2, 0, 0, 0);
      }
      int n = nc * 128 + w * 16 + l15;
      float bv = bqkv[n];
#pragma unroll
      for (int r = 0; r < 4; r++) {
        int m = m0 + quad * 4 + r;
        float v = a2[r] + bv;
        if (n < ND) Qb[(size_t)m * ND + n] = (__bf16)(v * QSCALE);
        else if (n < 2 * ND) Kb[(size_t)m * ND + n - ND] = (__bf16)v;
        else {
          int c2 = n - 2 * ND, hh = c2 >> 4, d0 = c2 & 15;
          int bb2 = m >> 11, nn = m & 2047;
          Vt[((size_t)((bb2 * NH + hh) * NDH + d0)) * NN + nn] = (__bf16)v;
        }
      }
    }
  }

  if constexpr (LAST) {
    if (w < NB) {
      int rt = root_idx[w];
      int rglob = w * NN + rt;
      if (rglob >= m0 && rglob < m0 + 16) {
        int r = rglob - m0;
        float v0 = Hs[r][2 * lane], v1 = Hs[r][2 * lane + 1];
        float s1 = v0 + v1, s2 = v0 * v0 + v1 * v1;
#pragma unroll
        for (int m = 32; m >= 1; m >>= 1) {
          s1 += __shfl_xor(s1, m, 64);
          s2 += __shfl_xor(s2, m, 64);
        }
        float mean = s1 * (1.0f / ND);
        float var = s2 * (1.0f / ND) - mean * mean;
        float rstd = rsqrtf(var + LN_EPS);
        float p0 = (v0 - mean) * rstd * hg[2 * lane] + hbt[2 * lane];
        float p1 = (v1 - mean) * rstd * hg[2 * lane + 1] + hbt[2 * lane + 1];
        float part = p0 * hwp[2 * lane] + p1 * hwp[2 * lane + 1];
#pragma unroll
        for (int m = 32; m >= 1; m >>= 1) part += __shfl_xor(part, m, 64);
        if (lane == 0) outp[w] = part + hbp[0];
      }
    }
  }
}

// ---------------- MFMA flash attention v7 (R9/R11, unchanged) ----------------
__global__ __launch_bounds__(512) void attn_kernel(
    const __bf16* __restrict__ Qb, const __bf16* __restrict__ Kb,
    const __bf16* __restrict__ Vt, const unsigned int* __restrict__ adjbits,
    const unsigned int* __restrict__ maskbits, const int* __restrict__ mask,
    const float* __restrict__ sbias, int layer, __bf16* __restrict__ o) {
  int b = blockIdx.z, hh = blockIdx.y, q0 = blockIdx.x * 32;
  int wave = threadIdx.x >> 6;
  int lane = threadIdx.x & 63;
  int l31 = lane & 31, hi = lane >> 5;
  int l15 = lane & 15, quad = lane >> 4;
  float esb = __expf(sbias[layer]);
  const int bN = b * NN;
  const int kw0 = wave * 256;

  __shared__ __bf16 Pbuf[8][32][40];
  __shared__ float Ored[8][32][17];
  __shared__ float Lred[8][32];

  bf8_t Qf = *(const bf8_t*)(Qb + (size_t)(bN + q0 + l31) * ND + hh * NDH + hi * 8);

  int q = q0 + l31;
  int mq = mask[bN + q];
  const unsigned int* adjp = adjbits + (size_t)(bN + q) * (NN / 32) + (kw0 >> 5);
  const unsigned int* mbp = maskbits + (bN + kw0) / 32;
  const __bf16* kp = Kb + (size_t)(bN + kw0 + l31) * ND + hh * NDH + hi * 8;
  const __bf16* vp = Vt + (size_t)((b * NH + hh) * NDH + l15) * NN + kw0 + quad * 8;

  int dq = q - kw0;
  int tsel = dq >> 5;
  unsigned int selfw = 1u << (dq & 31);
  int sh4 = hi * 4;

  f4x Olo = {0.f, 0.f, 0.f, 0.f}, Ohi = {0.f, 0.f, 0.f, 0.f};
  float ls = 0.f;

  bf8_t Kf = *(const bf8_t*)kp;
  bf8_t Vf = *(const bf8_t*)vp;
  unsigned int aw = adjp[0];
  unsigned int mkw = mbp[0];

  for (int t = 0; t < 8; t++) {
    bf8_t Kn = Kf, Vn = Vf;
    unsigned int awn = aw, mkn = mkw;
    if (t < 7) {
      kp += 32 * ND;
      Kn = *(const bf8_t*)kp;
      Vn = *(const bf8_t*)(vp + (t + 1) * 32);
      awn = adjp[t + 1];
      mkn = mbp[t + 1];
    }
    f16x S = {0.f, 0.f, 0.f, 0.f, 0.f, 0.f, 0.f, 0.f,
              0.f, 0.f, 0.f, 0.f, 0.f, 0.f, 0.f, 0.f};
    S = __builtin_amdgcn_mfma_f32_32x32x16_bf16(Kf, Qf, S, 0, 0, 0);
    unsigned int okw = mq ? mkw : ((t == tsel) ? selfw : 0u);
    unsigned int wa = (aw & okw) >> sh4;
    unsigned int okh = okw >> sh4;
#pragma unroll
    for (int gg = 0; gg < 4; gg++) {
      bf4_t pk;
#pragma unroll
      for (int r = 0; r < 4; r++) {
        int c = gg * 8 + r;
        float e = __builtin_amdgcn_exp2f(S[gg * 4 + r]);
        float wgt = ((wa >> c) & 1) ? esb : (((okh >> c) & 1) ? 1.0f : 0.0f);
        float p = e * wgt;
        ls += p;
        pk[r] = (__bf16)p;
      }
      *(bf4_t*)&Pbuf[wave][l31][sh4 + gg * 8] = pk;
    }
    asm volatile("s_waitcnt lgkmcnt(0)" ::: "memory");
    bf8_t Plo = *(const bf8_t*)&Pbuf[wave][l15][quad * 8];
    bf8_t Phi = *(const bf8_t*)&Pbuf[wave][16 + l15][quad * 8];
    Olo = __builtin_amdgcn_mfma_f32_16x16x32_bf16(Plo, Vf, Olo, 0, 0, 0);
    Ohi = __builtin_amdgcn_mfma_f32_16x16x32_bf16(Phi, Vf, Ohi, 0, 0, 0);
    Kf = Kn; Vf = Vn; aw = awn; mkw = mkn;
  }

  ls += __shfl_xor(ls, 32, 64);
  if (hi == 0) Lred[wave][l31] = ls;
#pragma unroll
  for (int r = 0; r < 4; r++) {
    Ored[wave][quad * 4 + r][l15] = Olo[r];
    Ored[wave][16 + quad * 4 + r][l15] = Ohi[r];
  }
  __syncthreads();
  int row = threadIdx.x >> 4, col = threadIdx.x & 15;
  float s = 0.f, L = 0.f;
#pragma unroll
  for (int p = 0; p < 8; p++) {
    s += Ored[p][row][col];
    L += Lred[p][row];
  }
  o[(size_t)(bN + q0 + row) * ND + hh * NDH + col] = (__bf16)(s / L);
}

extern "C" void kernel_launch(void* const* d_in, const int* in_sizes, int n_in,
                              void* d_out, int out_size, void* d_ws, size_t ws_size,
                              hipStream_t stream) {
  const float* atom_embed = (const float*)d_in[0];
  const float* cons_embed = (const float*)d_in[1];
  const float* in_w  = (const float*)d_in[2];
  const float* in_b  = (const float*)d_in[3];
  const float* qkv_w = (const float*)d_in[4];
  const float* qkv_b = (const float*)d_in[5];
  const float* out_w = (const float*)d_in[6];
  const float* out_b = (const float*)d_in[7];
  const float* ln1_g = (const float*)d_in[8];
  const float* ln1_b = (const float*)d_in[9];
  const float* ln2_g = (const float*)d_in[10];
  const float* ln2_b = (const float*)d_in[11];
  const float* ff1_w = (const float*)d_in[12];
  const float* ff1_b = (const float*)d_in[13];
  const float* ff2_w = (const float*)d_in[14];
  const float* ff2_b = (const float*)d_in[15];
  const float* sbias = (const float*)d_in[16];
  const float* hg    = (const float*)d_in[17];
  const float* hbt   = (const float*)d_in[18];
  const float* hw    = (const float*)d_in[19];
  const float* hb    = (const float*)d_in[20];
  const float* adj   = (const float*)d_in[21];
  const int* is_atom = (const int*)d_in[22];
  const int* atom_id = (const int*)d_in[23];
  const int* mask    = (const int*)d_in[24];
  const int* root_idx= (const int*)d_in[25];
  float* out = (float*)d_out;

  const int MR = NB * NN;  // 4096 rows
  float* hA = (float*)d_ws;
  float* hB = hA + MR * ND;
  __bf16* Qb   = (__bf16*)(hB + MR * ND);
  __bf16* Kb   = Qb + MR * ND;
  __bf16* Vt   = Kb + MR * ND;
  __bf16* wbqkv= Vt + MR * ND;                  // 147456 (layer 0 slice unused)
  __bf16* wbout= wbqkv + NL * 384 * ND;         // 49152
  __bf16* wbff1= wbout + NL * ND * ND;          // 196608
  __bf16* wbff2= wbff1 + NL * 512 * ND;         // 196608
  unsigned int* adjb = (unsigned int*)(wbff2 + NL * ND * 512);
  unsigned int* mskb = adjb + NB * NN * NN / 32;
  __bf16* ob = (__bf16*)(mskb + 128);

  EntryArgs ea;
  ea.atom_embed = atom_embed; ea.cons_embed = cons_embed;
  ea.is_atom = is_atom; ea.atom_id = atom_id;
  ea.in_w = in_w; ea.in_b = in_b;
  ea.qkv_w = qkv_w; ea.qkv_b = qkv_b;
  ea.ln1_g = ln1_g; ea.ln1_b = ln1_b;
  ea.hA = hA; ea.Qb = Qb; ea.Kb = Kb; ea.Vt = Vt;
  ea.out_w = out_w; ea.ff1_w = ff1_w; ea.ff2_w = ff2_w;
  ea.wbqkv = wbqkv; ea.wbout = wbout; ea.wbff1 = wbff1; ea.wbff2 = wbff2;
  ea.adj = adj; ea.abits = (unsigned long long*)adjb;
  ea.mask = mask; ea.mbits = (unsigned long long*)mskb;
  entry_kernel<<<1603, 512, 0, stream>>>(ea);

  const float* hin[3]  = {hA, hB, hA};
  float* hout[3]       = {hB, hA, hB};
  for (int i = 0; i < NL; i++) {
    attn_kernel<<<dim3(NN / 32, NH, NB), 512, 0, stream>>>(
        Qb, Kb, Vt, adjb, mskb, mask, sbias, i, ob);
    if (i < NL - 1) {
      layer_kernel<0><<<dim3(MR / 16, 2), 512, 0, stream>>>(
          ob, wbout + (size_t)i * ND * ND, out_b + i * ND, hin[i], hout[i],
          ln2_g + i * ND, ln2_b + i * ND,
          wbff1 + (size_t)i * 512 * ND, ff1_b + i * 512,
          wbff2 + (size_t)i * ND * 512, ff2_b + i * ND,
          ln1_g + (i + 1) * ND, ln1_b + (i + 1) * ND,
          wbqkv + (size_t)(i + 1) * 384 * ND, qkv_b + (i + 1) * 384,
          Qb, Kb, Vt,
          nullptr, nullptr, nullptr, nullptr, nullptr, nullptr);
    } else {
      layer_kernel<1><<<dim3(MR / 16, 1), 512, 0, stream>>>(
          ob, wbout + (size_t)i * ND * ND, out_b + i * ND, hin[i], hout[i],
          ln2_g + i * ND, ln2_b + i * ND,
          wbff1 + (size_t)i * 512 * ND, ff1_b + i * 512,
          wbff2 + (size_t)i * ND * 512, ff2_b + i * ND,
          nullptr, nullptr, nullptr, nullptr,
          nullptr, nullptr, nullptr,
          root_idx, hg, hbt, hw, hb, out);
    }
  }
}

// Round 14
// 261.002 us; speedup vs baseline: 2.2062x; 1.0311x over previous
//
#include <hip/hip_runtime.h>
#include <cmath>

#define NB 2
#define NN 2048
#define ND 128
#define NH 8
#define NL 3
#define NV 32
#define NDH 16
#define LN_EPS 1e-5f
/* ATT_SCALE(0.25) * log2(e), folded into Q at qkv-pack time so the attention
   inner loop is a raw exp2 per score. */
#define QSCALE 0.36067376022224085f

typedef __bf16 bf8_t __attribute__((ext_vector_type(8)));
typedef __bf16 bf4_t __attribute__((ext_vector_type(4)));
typedef float f4x __attribute__((ext_vector_type(4)));
typedef float f16x __attribute__((ext_vector_type(16)));

// ---------------- one prep kernel: weight casts + adjacency/mask bitpack ----
struct CastArgs {
  const float* s[5];
  __bf16* d[5];
  int startblk[5];
};
// blocks [0,592): casts; [592, 592+8192): adj bitpack; [8784, 8800): mask bitpack
__global__ __launch_bounds__(256) void prep_kernel(
    CastArgs a, const float* __restrict__ adj, unsigned long long* __restrict__ abits,
    const int* __restrict__ mask, unsigned long long* __restrict__ mbits) {
  int blk = blockIdx.x;
  int lane = threadIdx.x & 63;
  if (blk < 592) {
    int seg = 0;
#pragma unroll
    for (int i = 1; i < 5; i++) seg += (blk >= a.startblk[i]) ? 1 : 0;
    int i4 = (blk - a.startblk[seg]) * 256 + threadIdx.x;
    float4 v = ((const float4*)a.s[seg])[i4];
    bf4_t p = {(__bf16)v.x, (__bf16)v.y, (__bf16)v.z, (__bf16)v.w};
    ((bf4_t*)a.d[seg])[i4] = p;
  } else if (blk < 592 + 8192) {
    int g = ((blk - 592) * 4 + (threadIdx.x >> 6)) * 4;
    const float* p = adj + (size_t)g * 64 + lane;
    unsigned long long w0 = __ballot(p[0] != 0.0f);
    unsigned long long w1 = __ballot(p[64] != 0.0f);
    unsigned long long w2 = __ballot(p[128] != 0.0f);
    unsigned long long w3 = __ballot(p[192] != 0.0f);
    if (lane == 0) {
      abits[g] = w0; abits[g + 1] = w1; abits[g + 2] = w2; abits[g + 3] = w3;
    }
  } else {
    int g = (blk - 8784) * 4 + (threadIdx.x >> 6);
    int v = mask[g * 64 + lane];
    unsigned long long bal = __ballot(v != 0);
    if (lane == 0) mbits[g] = bal;
  }
}

// ---------------- fused0: embed + in-proj + LN1[0] + qkv[0] ----
__global__ __launch_bounds__(512) void fused0_kernel(
    const float* __restrict__ atom_embed, const float* __restrict__ cons_embed,
    const int* __restrict__ is_atom, const int* __restrict__ atom_id,
    const __bf16* __restrict__ W1, const float* __restrict__ b1,
    float* __restrict__ Hout,
    const float* __restrict__ lng, const float* __restrict__ lnb,
    const __bf16* __restrict__ W2, const float* __restrict__ b2,
    __bf16* __restrict__ Qb, __bf16* __restrict__ Kb, __bf16* __restrict__ Vt) {
  __shared__ __bf16 Xs[16][136];
  __shared__ __bf16 Ws[128][136];
  __shared__ float Hs[16][132];
  __shared__ __bf16 X2[16][136];
  int m0 = blockIdx.x * 16;
  int g = blockIdx.y;
  int t = threadIdx.x;
  int lane = t & 63, w = t >> 6;
  int l15 = lane & 15, quad = lane >> 4;
  const int NC2 = (g == 0) ? 2 : 1;
  const int T = 1 + NC2;

  {
    int r = t >> 5, c = t & 31;
    int row = m0 + r;
    int id = atom_id[row];
    id = id < 0 ? 0 : (id > NV - 1 ? NV - 1 : id);
    const float* src = is_atom[row] ? (atom_embed + (size_t)id * ND) : cons_embed;
    float4 v = *(const float4*)&src[c * 4];
    bf4_t p = {(__bf16)v.x, (__bf16)v.y, (__bf16)v.z, (__bf16)v.w};
    *(bf4_t*)&Xs[r][c * 4] = p;
  }

  bf8_t wreg[4];
  auto issue = [&](int i) {
    const __bf16* base;
    int rowoff;
    if (i == 0) { base = W1; rowoff = 0; }
    else {
      int nc = (g == 0) ? (i - 1) : 2;
      base = W2; rowoff = nc * 128;
    }
#pragma unroll
    for (int jj = 0; jj < 4; jj++) {
      int c = t + jj * 512;
      wreg[jj] = *(const bf8_t*)&base[(size_t)(rowoff + (c >> 4)) * 128 + (c & 15) * 8];
    }
  };
  issue(0);

  for (int i = 0; i < T; i++) {
    if (i) __syncthreads();
#pragma unroll
    for (int jj = 0; jj < 4; jj++) {
      int c = t + jj * 512;
      *(bf8_t*)&Ws[c >> 4][(c & 15) * 8] = wreg[jj];
    }
    __syncthreads();
    if (i + 1 < T) issue(i + 1);
    if (i == 0) {
      f4x a1 = {0.f, 0.f, 0.f, 0.f};
#pragma unroll
      for (int kk = 0; kk < 4; kk++) {
        bf8_t a = *(const bf8_t*)&Xs[l15][kk * 32 + quad * 8];
        bf8_t b = *(const bf8_t*)&Ws[w * 16 + l15][kk * 32 + quad * 8];
        a1 = __builtin_amdgcn_mfma_f32_16x16x32_bf16(a, b, a1, 0, 0, 0);
      }
      int n = w * 16 + l15;
      float bv = b1[n];
#pragma unroll
      for (int r = 0; r < 4; r++) {
        int m = quad * 4 + r;
        float v = a1[r] + bv;
        if (g == 0) Hout[(size_t)(m0 + m) * ND + n] = v;
        Hs[m][n] = v;
      }
      __syncthreads();
      {
        int r = t >> 5, c = t & 31;
        float4 v = *(const float4*)&Hs[r][c * 4];
        float s1 = v.x + v.y + v.z + v.w;
        float s2 = v.x * v.x + v.y * v.y + v.z * v.z + v.w * v.w;
#pragma unroll
        for (int m = 16; m >= 1; m >>= 1) {
          s1 += __shfl_xor(s1, m, 64);
          s2 += __shfl_xor(s2, m, 64);
        }
        float mean = s1 * (1.0f / ND);
        float var = s2 * (1.0f / ND) - mean * mean;
        float rstd = rsqrtf(var + LN_EPS);
        float4 gg = *(const float4*)&lng[c * 4];
        float4 bb = *(const float4*)&lnb[c * 4];
        bf4_t p;
        p[0] = (__bf16)((v.x - mean) * rstd * gg.x + bb.x);
        p[1] = (__bf16)((v.y - mean) * rstd * gg.y + bb.y);
        p[2] = (__bf16)((v.z - mean) * rstd * gg.z + bb.z);
        p[3] = (__bf16)((v.w - mean) * rstd * gg.w + bb.w);
        *(bf4_t*)&X2[r][c * 4] = p;
      }
    } else {
      int nc = (g == 0) ? (i - 1) : 2;
      f4x a2 = {0.f, 0.f, 0.f, 0.f};
#pragma unroll
      for (int kk = 0; kk < 4; kk++) {
        bf8_t a = *(const bf8_t*)&X2[l15][kk * 32 + quad * 8];
        bf8_t b = *(const bf8_t*)&Ws[w * 16 + l15][kk * 32 + quad * 8];
        a2 = __builtin_amdgcn_mfma_f32_16x16x32_bf16(a, b, a2, 0, 0, 0);
      }
      int n = nc * 128 + w * 16 + l15;
      float bv = b2[n];
#pragma unroll
      for (int r = 0; r < 4; r++) {
        int m = m0 + quad * 4 + r;
        float v = a2[r] + bv;
        if (n < ND) Qb[(size_t)m * ND + n] = (__bf16)(v * QSCALE);
        else if (n < 2 * ND) Kb[(size_t)m * ND + n - ND] = (__bf16)v;
        else {
          int c2 = n - 2 * ND, hh = c2 >> 4, d0 = c2 & 15;
          int bb2 = m >> 11, nn = m & 2047;
          Vt[((size_t)((bb2 * NH + hh) * NDH + d0)) * NN + nn] = (__bf16)v;
        }
      }
    }
  }
}

// ---------------- per-layer mega kernel ----------------
// Block = 16 rows, 512 threads, grid (256, LAST?1:2). Whole inter-attention
// segment in one launch: out-proj + res(Hin) + LN2 + ff1 + gelu (LDS Fs) +
// ff2 (K=512, 4 k-chunks) + res (Hs in-place) -> Hout + LN1[i+1] + qkv[i+1].
// Rolling register prefetch of each 128x128 weight tile hides L2 staging.
template <int LAST>
__global__ __launch_bounds__(512) void layer_kernel(
    const __bf16* __restrict__ Ob,
    const __bf16* __restrict__ Wout, const float* __restrict__ bout,
    const float* __restrict__ Hin, float* __restrict__ Hout,
    const float* __restrict__ ln2g, const float* __restrict__ ln2b,
    const __bf16* __restrict__ Wff1, const float* __restrict__ bff1,
    const __bf16* __restrict__ Wff2, const float* __restrict__ bff2,
    const float* __restrict__ ln1g, const float* __restrict__ ln1b,
    const __bf16* __restrict__ Wqkv, const float* __restrict__ bqkv,
    __bf16* __restrict__ Qb, __bf16* __restrict__ Kb, __bf16* __restrict__ Vt,
    const int* __restrict__ root_idx, const float* __restrict__ hg,
    const float* __restrict__ hbt, const float* __restrict__ hwp,
    const float* __restrict__ hbp, float* __restrict__ outp) {
  __shared__ __bf16 Xs[16][136];
  __shared__ __bf16 Ws[128][136];
  __shared__ float Hs[16][132];
  __shared__ __bf16 X2[16][136];
  __shared__ __bf16 Fs[16][520];
  int m0 = blockIdx.x * 16;
  int g = blockIdx.y;
  int t = threadIdx.x;
  int lane = t & 63, w = t >> 6;
  int l15 = lane & 15, quad = lane >> 4;
  const int NQ = LAST ? 0 : (g == 0 ? 2 : 1);
  const int T = 9 + NQ;

  {
    int r = t >> 5, c = t & 31;
    *(bf4_t*)&Xs[r][c * 4] = *(const bf4_t*)&Ob[(size_t)(m0 + r) * ND + c * 4];
  }

  bf8_t wreg[4];
  auto issue = [&](int i) {
    const __bf16* base;
    int stride, rowoff, coloff;
    if (i == 0)     { base = Wout; stride = 128; rowoff = 0;             coloff = 0; }
    else if (i < 5) { base = Wff1; stride = 128; rowoff = (i - 1) * 128; coloff = 0; }
    else if (i < 9) { base = Wff2; stride = 512; rowoff = 0;             coloff = (i - 5) * 128; }
    else            { int nc = (g == 0) ? (i - 9) : 2;
                      base = Wqkv; stride = 128; rowoff = nc * 128;      coloff = 0; }
#pragma unroll
    for (int jj = 0; jj < 4; jj++) {
      int c = t + jj * 512;
      wreg[jj] = *(const bf8_t*)&base[(size_t)(rowoff + (c >> 4)) * stride + coloff + (c & 15) * 8];
    }
  };
  issue(0);

  auto do_ln = [&](const float* g_, const float* b_) {
    int r = t >> 5, c = t & 31;
    float4 v = *(const float4*)&Hs[r][c * 4];
    float s1 = v.x + v.y + v.z + v.w;
    float s2 = v.x * v.x + v.y * v.y + v.z * v.z + v.w * v.w;
#pragma unroll
    for (int m = 16; m >= 1; m >>= 1) {
      s1 += __shfl_xor(s1, m, 64);
      s2 += __shfl_xor(s2, m, 64);
    }
    float mean = s1 * (1.0f / ND);
    float var = s2 * (1.0f / ND) - mean * mean;
    float rstd = rsqrtf(var + LN_EPS);
    float4 gg = *(const float4*)&g_[c * 4];
    float4 bb = *(const float4*)&b_[c * 4];
    bf4_t p;
    p[0] = (__bf16)((v.x - mean) * rstd * gg.x + bb.x);
    p[1] = (__bf16)((v.y - mean) * rstd * gg.y + bb.y);
    p[2] = (__bf16)((v.z - mean) * rstd * gg.z + bb.z);
    p[3] = (__bf16)((v.w - mean) * rstd * gg.w + bb.w);
    *(bf4_t*)&X2[r][c * 4] = p;
  };

  f4x acc2 = {0.f, 0.f, 0.f, 0.f};
  for (int i = 0; i < T; i++) {
    if (i) __syncthreads();
#pragma unroll
    for (int jj = 0; jj < 4; jj++) {
      int c = t + jj * 512;
      *(bf8_t*)&Ws[c >> 4][(c & 15) * 8] = wreg[jj];
    }
    __syncthreads();
    if (i + 1 < T) issue(i + 1);
    if (i == 0) {
      f4x a1 = {0.f, 0.f, 0.f, 0.f};
#pragma unroll
      for (int kk = 0; kk < 4; kk++) {
        bf8_t a = *(const bf8_t*)&Xs[l15][kk * 32 + quad * 8];
        bf8_t b = *(const bf8_t*)&Ws[w * 16 + l15][kk * 32 + quad * 8];
        a1 = __builtin_amdgcn_mfma_f32_16x16x32_bf16(a, b, a1, 0, 0, 0);
      }
      int n = w * 16 + l15;
      float bv = bout[n];
#pragma unroll
      for (int r = 0; r < 4; r++) {
        int m = quad * 4 + r;
        Hs[m][n] = a1[r] + bv + Hin[(size_t)(m0 + m) * ND + n];
      }
      __syncthreads();
      do_ln(ln2g, ln2b);
    } else if (i < 5) {
      int c = i - 1;
      f4x a1 = {0.f, 0.f, 0.f, 0.f};
#pragma unroll
      for (int kk = 0; kk < 4; kk++) {
        bf8_t a = *(const bf8_t*)&X2[l15][kk * 32 + quad * 8];
        bf8_t b = *(const bf8_t*)&Ws[w * 16 + l15][kk * 32 + quad * 8];
        a1 = __builtin_amdgcn_mfma_f32_16x16x32_bf16(a, b, a1, 0, 0, 0);
      }
      int n = w * 16 + l15;
      float bv = bff1[c * 128 + n];
#pragma unroll
      for (int r = 0; r < 4; r++) {
        float v = a1[r] + bv;
        v = 0.5f * v * (1.0f + erff(v * 0.70710678118f));
        Fs[quad * 4 + r][c * 128 + n] = (__bf16)v;
      }
    } else if (i < 9) {
      int j = i - 5;
#pragma unroll
      for (int kk = 0; kk < 4; kk++) {
        bf8_t a = *(const bf8_t*)&Fs[l15][j * 128 + kk * 32 + quad * 8];
        bf8_t b = *(const bf8_t*)&Ws[w * 16 + l15][kk * 32 + quad * 8];
        acc2 = __builtin_amdgcn_mfma_f32_16x16x32_bf16(a, b, acc2, 0, 0, 0);
      }
      if (j == 3) {
        int n = w * 16 + l15;
        float bv = bff2[n];
#pragma unroll
        for (int r = 0; r < 4; r++) {
          int m = quad * 4 + r;
          float v = acc2[r] + bv + Hs[m][n];
          Hs[m][n] = v;
          if (g == 0) Hout[(size_t)(m0 + m) * ND + n] = v;
        }
        __syncthreads();
        if constexpr (!LAST) do_ln(ln1g, ln1b);
      }
    } else {
      int nc = (g == 0) ? (i - 9) : 2;
      f4x a2 = {0.f, 0.f, 0.f, 0.f};
#pragma unroll
      for (int kk = 0; kk < 4; kk++) {
        bf8_t a = *(const bf8_t*)&X2[l15][kk * 32 + quad * 8];
        bf8_t b = *(const bf8_t*)&Ws[w * 16 + l15][kk * 32 + quad * 8];
        a2 = __builtin_amdgcn_mfma_f32_16x16x32_bf16(a, b, a2, 0, 0, 0);
      }
      int n = nc * 128 + w * 16 + l15;
      float bv = bqkv[n];
#pragma unroll
      for (int r = 0; r < 4; r++) {
        int m = m0 + quad * 4 + r;
        float v = a2[r] + bv;
        if (n < ND) Qb[(size_t)m * ND + n] = (__bf16)(v * QSCALE);
        else if (n < 2 * ND) Kb[(size_t)m * ND + n - ND] = (__bf16)v;
        else {
          int c2 = n - 2 * ND, hh = c2 >> 4, d0 = c2 & 15;
          int bb2 = m >> 11, nn = m & 2047;
          Vt[((size_t)((bb2 * NH + hh) * NDH + d0)) * NN + nn] = (__bf16)v;
        }
      }
    }
  }

  if constexpr (LAST) {
    if (w < NB) {
      int rt = root_idx[w];
      int rglob = w * NN + rt;
      if (rglob >= m0 && rglob < m0 + 16) {
        int r = rglob - m0;
        float v0 = Hs[r][2 * lane], v1 = Hs[r][2 * lane + 1];
        float s1 = v0 + v1, s2 = v0 * v0 + v1 * v1;
#pragma unroll
        for (int m = 32; m >= 1; m >>= 1) {
          s1 += __shfl_xor(s1, m, 64);
          s2 += __shfl_xor(s2, m, 64);
        }
        float mean = s1 * (1.0f / ND);
        float var = s2 * (1.0f / ND) - mean * mean;
        float rstd = rsqrtf(var + LN_EPS);
        float p0 = (v0 - mean) * rstd * hg[2 * lane] + hbt[2 * lane];
        float p1 = (v1 - mean) * rstd * hg[2 * lane + 1] + hbt[2 * lane + 1];
        float part = p0 * hwp[2 * lane] + p1 * hwp[2 * lane + 1];
#pragma unroll
        for (int m = 32; m >= 1; m >>= 1) part += __shfl_xor(part, m, 64);
        if (lane == 0) outp[w] = part + hbp[0];
      }
    }
  }
}

// ---------------- MFMA flash attention v7 ----------------
__global__ __launch_bounds__(512) void attn_kernel(
    const __bf16* __restrict__ Qb, const __bf16* __restrict__ Kb,
    const __bf16* __restrict__ Vt, const unsigned int* __restrict__ adjbits,
    const unsigned int* __restrict__ maskbits, const int* __restrict__ mask,
    const float* __restrict__ sbias, int layer, __bf16* __restrict__ o) {
  int b = blockIdx.z, hh = blockIdx.y, q0 = blockIdx.x * 32;
  int wave = threadIdx.x >> 6;
  int lane = threadIdx.x & 63;
  int l31 = lane & 31, hi = lane >> 5;
  int l15 = lane & 15, quad = lane >> 4;
  float esb = __expf(sbias[layer]);
  const int bN = b * NN;
  const int kw0 = wave * 256;

  __shared__ __bf16 Pbuf[8][32][40];
  __shared__ float Ored[8][32][17];
  __shared__ float Lred[8][32];

  bf8_t Qf = *(const bf8_t*)(Qb + (size_t)(bN + q0 + l31) * ND + hh * NDH + hi * 8);

  int q = q0 + l31;
  int mq = mask[bN + q];
  const unsigned int* adjp = adjbits + (size_t)(bN + q) * (NN / 32) + (kw0 >> 5);
  const unsigned int* mbp = maskbits + (bN + kw0) / 32;
  const __bf16* kp = Kb + (size_t)(bN + kw0 + l31) * ND + hh * NDH + hi * 8;
  const __bf16* vp = Vt + (size_t)((b * NH + hh) * NDH + l15) * NN + kw0 + quad * 8;

  int dq = q - kw0;
  int tsel = dq >> 5;
  unsigned int selfw = 1u << (dq & 31);
  int sh4 = hi * 4;

  f4x Olo = {0.f, 0.f, 0.f, 0.f}, Ohi = {0.f, 0.f, 0.f, 0.f};
  float ls = 0.f;

  bf8_t Kf = *(const bf8_t*)kp;
  bf8_t Vf = *(const bf8_t*)vp;
  unsigned int aw = adjp[0];
  unsigned int mkw = mbp[0];

  for (int t = 0; t < 8; t++) {
    bf8_t Kn = Kf, Vn = Vf;
    unsigned int awn = aw, mkn = mkw;
    if (t < 7) {
      kp += 32 * ND;
      Kn = *(const bf8_t*)kp;
      Vn = *(const bf8_t*)(vp + (t + 1) * 32);
      awn = adjp[t + 1];
      mkn = mbp[t + 1];
    }
    f16x S = {0.f, 0.f, 0.f, 0.f, 0.f, 0.f, 0.f, 0.f,
              0.f, 0.f, 0.f, 0.f, 0.f, 0.f, 0.f, 0.f};
    S = __builtin_amdgcn_mfma_f32_32x32x16_bf16(Kf, Qf, S, 0, 0, 0);
    unsigned int okw = mq ? mkw : ((t == tsel) ? selfw : 0u);
    unsigned int wa = (aw & okw) >> sh4;
    unsigned int okh = okw >> sh4;
#pragma unroll
    for (int gg = 0; gg < 4; gg++) {
      bf4_t pk;
#pragma unroll
      for (int r = 0; r < 4; r++) {
        int c = gg * 8 + r;
        float e = __builtin_amdgcn_exp2f(S[gg * 4 + r]);
        float wgt = ((wa >> c) & 1) ? esb : (((okh >> c) & 1) ? 1.0f : 0.0f);
        float p = e * wgt;
        ls += p;
        pk[r] = (__bf16)p;
      }
      *(bf4_t*)&Pbuf[wave][l31][sh4 + gg * 8] = pk;
    }
    asm volatile("s_waitcnt lgkmcnt(0)" ::: "memory");
    bf8_t Plo = *(const bf8_t*)&Pbuf[wave][l15][quad * 8];
    bf8_t Phi = *(const bf8_t*)&Pbuf[wave][16 + l15][quad * 8];
    Olo = __builtin_amdgcn_mfma_f32_16x16x32_bf16(Plo, Vf, Olo, 0, 0, 0);
    Ohi = __builtin_amdgcn_mfma_f32_16x16x32_bf16(Phi, Vf, Ohi, 0, 0, 0);
    Kf = Kn; Vf = Vn; aw = awn; mkw = mkn;
  }

  ls += __shfl_xor(ls, 32, 64);
  if (hi == 0) Lred[wave][l31] = ls;
#pragma unroll
  for (int r = 0; r < 4; r++) {
    Ored[wave][quad * 4 + r][l15] = Olo[r];
    Ored[wave][16 + quad * 4 + r][l15] = Ohi[r];
  }
  __syncthreads();
  int row = threadIdx.x >> 4, col = threadIdx.x & 15;
  float s = 0.f, L = 0.f;
#pragma unroll
  for (int p = 0; p < 8; p++) {
    s += Ored[p][row][col];
    L += Lred[p][row];
  }
  o[(size_t)(bN + q0 + row) * ND + hh * NDH + col] = (__bf16)(s / L);
}

extern "C" void kernel_launch(void* const* d_in, const int* in_sizes, int n_in,
                              void* d_out, int out_size, void* d_ws, size_t ws_size,
                              hipStream_t stream) {
  const float* atom_embed = (const float*)d_in[0];
  const float* cons_embed = (const float*)d_in[1];
  const float* in_w  = (const float*)d_in[2];
  const float* in_b  = (const float*)d_in[3];
  const float* qkv_w = (const float*)d_in[4];
  const float* qkv_b = (const float*)d_in[5];
  const float* out_w = (const float*)d_in[6];
  const float* out_b = (const float*)d_in[7];
  const float* ln1_g = (const float*)d_in[8];
  const float* ln1_b = (const float*)d_in[9];
  const float* ln2_g = (const float*)d_in[10];
  const float* ln2_b = (const float*)d_in[11];
  const float* ff1_w = (const float*)d_in[12];
  const float* ff1_b = (const float*)d_in[13];
  const float* ff2_w = (const float*)d_in[14];
  const float* ff2_b = (const float*)d_in[15];
  const float* sbias = (const float*)d_in[16];
  const float* hg    = (const float*)d_in[17];
  const float* hbt   = (const float*)d_in[18];
  const float* hw    = (const float*)d_in[19];
  const float* hb    = (const float*)d_in[20];
  const float* adj   = (const float*)d_in[21];
  const int* is_atom = (const int*)d_in[22];
  const int* atom_id = (const int*)d_in[23];
  const int* mask    = (const int*)d_in[24];
  const int* root_idx= (const int*)d_in[25];
  float* out = (float*)d_out;

  const int MR = NB * NN;  // 4096 rows
  float* hA = (float*)d_ws;
  float* hB = hA + MR * ND;
  __bf16* Qb   = (__bf16*)(hB + MR * ND);
  __bf16* Kb   = Qb + MR * ND;
  __bf16* Vt   = Kb + MR * ND;
  __bf16* wbin = Vt + MR * ND;
  __bf16* wbqkv= wbin + ND * ND;
  __bf16* wbout= wbqkv + NL * 384 * ND;
  __bf16* wbff1= wbout + NL * ND * ND;
  __bf16* wbff2= wbff1 + NL * 512 * ND;
  unsigned int* adjb = (unsigned int*)(wbff2 + NL * ND * 512);
  unsigned int* mskb = adjb + NB * NN * NN / 32;
  __bf16* ob = (__bf16*)(mskb + 128);

  CastArgs ca;
  ca.s[0] = in_w;  ca.d[0] = wbin;  ca.startblk[0] = 0;
  ca.s[1] = qkv_w; ca.d[1] = wbqkv; ca.startblk[1] = 16;
  ca.s[2] = out_w; ca.d[2] = wbout; ca.startblk[2] = 160;
  ca.s[3] = ff1_w; ca.d[3] = wbff1; ca.startblk[3] = 208;
  ca.s[4] = ff2_w; ca.d[4] = wbff2; ca.startblk[4] = 400;
  prep_kernel<<<8800, 256, 0, stream>>>(ca, adj, (unsigned long long*)adjb,
                                        mask, (unsigned long long*)mskb);

  fused0_kernel<<<dim3(MR / 16, 2), 512, 0, stream>>>(
      atom_embed, cons_embed, is_atom, atom_id,
      wbin, in_b, hA, ln1_g, ln1_b, wbqkv, qkv_b, Qb, Kb, Vt);

  const float* hin[3]  = {hA, hB, hA};
  float* hout[3]       = {hB, hA, hB};
  for (int i = 0; i < NL; i++) {
    attn_kernel<<<dim3(NN / 32, NH, NB), 512, 0, stream>>>(
        Qb, Kb, Vt, adjb, mskb, mask, sbias, i, ob);
    if (i < NL - 1) {
      layer_kernel<0><<<dim3(MR / 16, 2), 512, 0, stream>>>(
          ob, wbout + (size_t)i * ND * ND, out_b + i * ND, hin[i], hout[i],
          ln2_g + i * ND, ln2_b + i * ND,
          wbff1 + (size_t)i * 512 * ND, ff1_b + i * 512,
          wbff2 + (size_t)i * ND * 512, ff2_b + i * ND,
          ln1_g + (i + 1) * ND, ln1_b + (i + 1) * ND,
          wbqkv + (size_t)(i + 1) * 384 * ND, qkv_b + (i + 1) * 384,
          Qb, Kb, Vt,
          nullptr, nullptr, nullptr, nullptr, nullptr, nullptr);
    } else {
      layer_kernel<1><<<dim3(MR / 16, 1), 512, 0, stream>>>(
          ob, wbout + (size_t)i * ND * ND, out_b + i * ND, hin[i], hout[i],
          ln2_g + i * ND, ln2_b + i * ND,
          wbff1 + (size_t)i * 512 * ND, ff1_b + i * 512,
          wbff2 + (size_t)i * ND * 512, ff2_b + i * ND,
          nullptr, nullptr, nullptr, nullptr,
          nullptr, nullptr, nullptr,
          root_idx, hg, hbt, hw, hb, out);
    }
  }
}